// Round 1
// baseline (171.129 us; speedup 1.0000x reference)
//
#include <hip/hip_runtime.h>
#include <stdint.h>

// Problem constants (MultiLinear): out[c,b,d] = sum_a in[a,b] * W[reg[c],a,d] + bias[reg[c],d]
#define A_DIM 512   // in_features  (K)
#define B_DIM 1024  // batch        (M)
#define D_DIM 512   // out_features (N)

typedef __bf16 bf16x8 __attribute__((ext_vector_type(8)));
typedef float f32x4 __attribute__((ext_vector_type(4)));

typedef __attribute__((address_space(1))) void gvoid_t;
typedef __attribute__((address_space(3))) void svoid_t;

// fp32 -> bf16 round-to-nearest-even (inputs are finite; NaN path irrelevant)
__device__ __forceinline__ unsigned short f2bf(float f) {
  union { float f; unsigned u; } x; x.f = f;
  unsigned r = x.u + 0x7fffu + ((x.u >> 16) & 1u);
  return (unsigned short)(r >> 16);
}

// async global->LDS, 16B per lane; LDS dest = wave-uniform base + lane*16
__device__ __forceinline__ void gload16(const void* g, void* l) {
  __builtin_amdgcn_global_load_lds((gvoid_t*)g, (svoid_t*)l, 16, 0, 0);
}

// ---------------------------------------------------------------------------
// Pass 1: tiled transpose + fp32->bf16 convert.
//   src: fp32 matrix (M rows x N cols), optionally gathered via idx[blockIdx.z]
//   dst: bf16 matrix [N][M] at dst + blockIdx.z*M*N
// 64x64 tiles, 256 threads. LDS T[64][65] fp32 breaks bank conflicts.
// ---------------------------------------------------------------------------
__global__ __launch_bounds__(256) void transpose_cvt(
    const float* __restrict__ src, unsigned short* __restrict__ dst,
    const int* __restrict__ idx, int M, int N) {
  __shared__ float T[64][65];
  const int t = threadIdx.x;
  const size_t mat = idx ? (size_t)idx[blockIdx.z] : 0;
  const float* s = src + mat * (size_t)M * N;
  unsigned short* d = dst + (size_t)blockIdx.z * (size_t)M * N;
  const int m0 = blockIdx.y * 64, n0 = blockIdx.x * 64;

  // load 64(m) x 64(n) fp32, store transposed into T[n_local][m_local]
#pragma unroll
  for (int p = 0; p < 4; ++p) {
    const int mr = (t >> 4) + p * 16;
    const int n4 = (t & 15) * 4;
    const float4 v = *(const float4*)(s + (size_t)(m0 + mr) * N + n0 + n4);
    T[n4 + 0][mr] = v.x;
    T[n4 + 1][mr] = v.y;
    T[n4 + 2][mr] = v.z;
    T[n4 + 3][mr] = v.w;
  }
  __syncthreads();

  // write rows of dst[n][m] as bf16, 16B (ushort8) per lane, coalesced
#pragma unroll
  for (int p = 0; p < 2; ++p) {
    const int nr = (t >> 3) + p * 32;
    const int m8 = (t & 7) * 8;
    alignas(16) unsigned short tmp[8];
#pragma unroll
    for (int j = 0; j < 8; ++j) tmp[j] = f2bf(T[nr][m8 + j]);
    *(uint4*)(d + (size_t)(n0 + nr) * M + m0 + m8) = *(const uint4*)tmp;
  }
}

// ---------------------------------------------------------------------------
// Pass 2: bf16 MFMA GEMM per region chunk (m97-style 128x128 tile, BK=32).
//   Xt: [B_DIM][A_DIM] bf16 (k-contiguous)
//   Wt: [nc][D_DIM][A_DIM] bf16 (k-contiguous), chunk-local
//   out[c,b,d] fp32 with bias added.
// 4 waves (2x2), each wave 64x64 = 4x4 fragments of 16x16x32.
// LDS staged via global_load_lds (linear dest) with XOR-swizzled global source;
// reads un-swizzle: 16B block s holds logical k-chunk s^(row&3).
// ---------------------------------------------------------------------------
__global__ __launch_bounds__(256, 2) void mlgemm(
    const unsigned short* __restrict__ Xt, const unsigned short* __restrict__ Wt,
    const float* __restrict__ bias_table, const int* __restrict__ regions,
    int c0, float* __restrict__ out) {
  __shared__ alignas(16) unsigned short As[2][128][32];
  __shared__ alignas(16) unsigned short Bs[2][128][32];

  const int t = threadIdx.x;
  const int w = t >> 6, l = t & 63;
  const int b0 = blockIdx.x * 128, d0 = blockIdx.y * 128;
  const int cc = blockIdx.z, c = c0 + cc;
  const int lr = l & 15, lg = l >> 4;
  const int wm = w & 1, wn = w >> 1;

  f32x4 acc[4][4] = {};

  const size_t xbase = (size_t)b0 * A_DIM;
  const size_t wbase = ((size_t)cc * D_DIM + d0) * A_DIM;

  auto stage = [&](int buf, int kt) {
#pragma unroll
    for (int i = 0; i < 2; ++i) {
      const int row = w * 32 + i * 16 + (l >> 2);
      const int seg = (l & 3) ^ (row & 3);  // pre-swizzle the SOURCE (rule #21)
      const int koff = kt * 32 + seg * 8;
      gload16(Xt + xbase + (size_t)row * A_DIM + koff, &As[buf][w * 32 + i * 16][0]);
      gload16(Wt + wbase + (size_t)row * A_DIM + koff, &Bs[buf][w * 32 + i * 16][0]);
    }
  };

  auto compute = [&](int buf) {
    bf16x8 av[4], bv[4];
#pragma unroll
    for (int m = 0; m < 4; ++m) {
      const int row = wm * 64 + m * 16 + lr;
      av[m] = *(const bf16x8*)&As[buf][row][(lg ^ (row & 3)) * 8];
    }
#pragma unroll
    for (int n = 0; n < 4; ++n) {
      const int row = wn * 64 + n * 16 + lr;
      bv[n] = *(const bf16x8*)&Bs[buf][row][(lg ^ (row & 3)) * 8];
    }
#pragma unroll
    for (int m = 0; m < 4; ++m)
#pragma unroll
      for (int n = 0; n < 4; ++n)
        acc[m][n] = __builtin_amdgcn_mfma_f32_16x16x32_bf16(av[m], bv[n], acc[m][n], 0, 0, 0);
  };

  stage(0, 0);
  __syncthreads();  // drains vmcnt(0) before barrier (compiler-emitted)
  int cur = 0;
#pragma unroll 1
  for (int kt = 0; kt < (A_DIM / 32) - 1; ++kt) {
    stage(cur ^ 1, kt + 1);  // async prefetch next K-tile
    compute(cur);
    __syncthreads();
    cur ^= 1;
  }
  compute(cur);

  // epilogue: bias + store (C/D map: col=lane&15, row=(lane>>4)*4+reg)
  const int h = regions[c];
  float bs[4];
#pragma unroll
  for (int n = 0; n < 4; ++n)
    bs[n] = bias_table[(size_t)h * D_DIM + d0 + wn * 64 + n * 16 + lr];

  float* ob = out + (size_t)c * B_DIM * D_DIM;
#pragma unroll
  for (int m = 0; m < 4; ++m) {
#pragma unroll
    for (int j = 0; j < 4; ++j) {
      const int bb = b0 + wm * 64 + m * 16 + lg * 4 + j;
      float* orow = ob + (size_t)bb * D_DIM + d0 + wn * 64 + lr;
#pragma unroll
      for (int n = 0; n < 4; ++n) orow[n * 16] = acc[m][n][j] + bs[n];
    }
  }
}

// ---------------------------------------------------------------------------
// Fallback (only if ws_size is too small for even one region): naive fp32.
// ---------------------------------------------------------------------------
__global__ __launch_bounds__(256) void naive_ml(
    const float* __restrict__ in, const int* __restrict__ regions,
    const float* __restrict__ wt, const float* __restrict__ bias,
    float* __restrict__ out) {
  const int d = blockIdx.x * 256 + threadIdx.x;
  const int b = blockIdx.y;
  const int cz = blockIdx.z;
  const int h = regions[cz];
  const float* W = wt + (size_t)h * A_DIM * D_DIM + d;
  float acc = bias[(size_t)h * D_DIM + d];
  for (int a = 0; a < A_DIM; ++a) acc += in[(size_t)a * B_DIM + b] * W[(size_t)a * D_DIM];
  out[(size_t)cz * B_DIM * D_DIM + (size_t)b * D_DIM + d] = acc;
}

extern "C" void kernel_launch(void* const* d_in, const int* in_sizes, int n_in,
                              void* d_out, int out_size, void* d_ws, size_t ws_size,
                              hipStream_t stream) {
  const float* input = (const float*)d_in[0];
  const int* regions = (const int*)d_in[1];
  const float* wtab  = (const float*)d_in[2];
  const float* btab  = (const float*)d_in[3];
  float* out = (float*)d_out;
  const int C = in_sizes[1];  // n_regions = 128

  const size_t xt_bytes   = (size_t)B_DIM * A_DIM * 2;  // 1 MB
  const size_t per_region = (size_t)D_DIM * A_DIM * 2;  // 512 KB

  int cap = 0;
  if (ws_size > xt_bytes) {
    size_t r = (ws_size - xt_bytes) / per_region;
    cap = (r > (size_t)C) ? C : (int)r;
  }
  if (cap < 1) {
    naive_ml<<<dim3(D_DIM / 256, B_DIM, C), 256, 0, stream>>>(input, regions, wtab, btab, out);
    return;
  }

  unsigned short* Xt = (unsigned short*)d_ws;
  unsigned short* Wt = (unsigned short*)((char*)d_ws + xt_bytes);

  // Xt[b][a] <- input[a][b] (bf16)
  transpose_cvt<<<dim3(B_DIM / 64, A_DIM / 64, 1), 256, 0, stream>>>(
      input, Xt, nullptr, A_DIM, B_DIM);

  // Chunked: Wt[cc][d][a] <- W[regions[c0+cc]][a][d] (bf16), then GEMM the chunk.
  for (int c0 = 0; c0 < C; c0 += cap) {
    const int nc = (C - c0 < cap) ? (C - c0) : cap;
    transpose_cvt<<<dim3(D_DIM / 64, A_DIM / 64, nc), 256, 0, stream>>>(
        wtab, Wt, regions + c0, A_DIM, D_DIM);
    mlgemm<<<dim3(B_DIM / 128, D_DIM / 128, nc), 256, 0, stream>>>(
        Xt, Wt, btab, regions, c0, out);
  }
}

// Round 2
// 168.482 us; speedup vs baseline: 1.0157x; 1.0157x over previous
//
#include <hip/hip_runtime.h>
#include <stdint.h>

// out[c,b,d] = sum_a in[a,b] * W[reg[c],a,d] + bias[reg[c],d]
#define A_DIM 512   // in_features  (K)
#define B_DIM 1024  // batch        (M)
#define D_DIM 512   // out_features (N)

typedef __bf16 bf16x8 __attribute__((ext_vector_type(8)));
typedef float f32x4 __attribute__((ext_vector_type(4)));

typedef __attribute__((address_space(1))) void gvoid_t;
typedef __attribute__((address_space(3))) void svoid_t;

#define WAITV8() asm volatile("s_waitcnt vmcnt(8)" ::: "memory")
#define WAITV4() asm volatile("s_waitcnt vmcnt(4)" ::: "memory")
#define WAITV0() asm volatile("s_waitcnt vmcnt(0)" ::: "memory")
#define BARRIER() do { asm volatile("" ::: "memory"); __builtin_amdgcn_s_barrier(); asm volatile("" ::: "memory"); } while (0)

__device__ __forceinline__ unsigned short f2bf(float f) {
  union { float f; unsigned u; } x; x.f = f;
  unsigned r = x.u + 0x7fffu + ((x.u >> 16) & 1u);
  return (unsigned short)(r >> 16);
}

__device__ __forceinline__ void gload16(const void* g, void* l) {
  __builtin_amdgcn_global_load_lds((gvoid_t*)g, (svoid_t*)l, 16, 0, 0);
}

// ---------------------------------------------------------------------------
// Pass 1: tiled transpose + fp32->bf16. 64x64 tiles, 256 threads.
// ---------------------------------------------------------------------------
__global__ __launch_bounds__(256) void transpose_cvt(
    const float* __restrict__ src, unsigned short* __restrict__ dst,
    const int* __restrict__ idx, int M, int N) {
  __shared__ float T[64][65];
  const int t = threadIdx.x;
  const size_t mat = idx ? (size_t)idx[blockIdx.z] : 0;
  const float* s = src + mat * (size_t)M * N;
  unsigned short* d = dst + (size_t)blockIdx.z * (size_t)M * N;
  const int m0 = blockIdx.y * 64, n0 = blockIdx.x * 64;

#pragma unroll
  for (int p = 0; p < 4; ++p) {
    const int mr = (t >> 4) + p * 16;
    const int n4 = (t & 15) * 4;
    const float4 v = *(const float4*)(s + (size_t)(m0 + mr) * N + n0 + n4);
    T[n4 + 0][mr] = v.x;
    T[n4 + 1][mr] = v.y;
    T[n4 + 2][mr] = v.z;
    T[n4 + 3][mr] = v.w;
  }
  __syncthreads();

#pragma unroll
  for (int p = 0; p < 2; ++p) {
    const int nr = (t >> 3) + p * 32;
    const int m8 = (t & 7) * 8;
    alignas(16) unsigned short tmp[8];
#pragma unroll
    for (int j = 0; j < 8; ++j) tmp[j] = f2bf(T[nr][m8 + j]);
    *(uint4*)(d + (size_t)(n0 + nr) * M + m0 + m8) = *(const uint4*)tmp;
  }
}

// ---------------------------------------------------------------------------
// Pass 2: 256x256-tile bf16 MFMA GEMM, BK=32, 8 waves (2M x 4N), 512 threads.
// 4-deep circular LDS buffer (128 KiB), counted vmcnt (never 0 in main loop),
// one s_barrier per K-tile, setprio around the MFMA cluster.
// LDS rows are 64B (BK=32) so wave fragment reads cover a contiguous 1KB
// region -> conflict-free without swizzle; staging dest is linear (rule #21
// satisfied trivially: neither side swizzled).
// ---------------------------------------------------------------------------
__global__ __launch_bounds__(512, 2) void mlgemm(
    const unsigned short* __restrict__ Xt, const unsigned short* __restrict__ Wt,
    const float* __restrict__ bias_table, const int* __restrict__ regions,
    int c0, float* __restrict__ out) {
  __shared__ alignas(16) unsigned short As[4][256][32];  // 64 KiB
  __shared__ alignas(16) unsigned short Bs[4][256][32];  // 64 KiB

  const int t = threadIdx.x;
  const int w = t >> 6, l = t & 63;
  const int lr = l & 15, lg = l >> 4;
  const int wm = w >> 2, wn = w & 3;              // 2 (M) x 4 (N) waves
  const int b0 = blockIdx.x * 256, d0 = blockIdx.y * 256;
  const int cc = blockIdx.z, c = c0 + cc;

  f32x4 acc[8][4] = {};

  const size_t xbase = (size_t)b0 * A_DIM;
  const size_t wbase = ((size_t)cc * D_DIM + d0) * A_DIM;

  // Stage K-tile t into buffer t&3. Per wave: 4 global_load_lds (2 A + 2 B).
  auto stage = [&](int t_) {
    const int buf = t_ & 3;
    const int koff = t_ * 32 + (l & 3) * 8;
    const int lrow_lane = (l >> 2);
#pragma unroll
    for (int r = 0; r < 2; ++r) {
      const int row0 = r * 128 + w * 16;           // wave-uniform
      const int lrow = row0 + lrow_lane;           // per-lane global source row
      gload16(Xt + xbase + (size_t)lrow * A_DIM + koff, &As[buf][row0][0]);
      gload16(Wt + wbase + (size_t)lrow * A_DIM + koff, &Bs[buf][row0][0]);
    }
  };

  auto compute = [&](int t_) {
    const int buf = t_ & 3;
    bf16x8 av[8], bv[4];
#pragma unroll
    for (int m = 0; m < 8; ++m)
      av[m] = *(const bf16x8*)&As[buf][wm * 128 + m * 16 + lr][lg * 8];
#pragma unroll
    for (int n = 0; n < 4; ++n)
      bv[n] = *(const bf16x8*)&Bs[buf][wn * 64 + n * 16 + lr][lg * 8];
    __builtin_amdgcn_s_setprio(1);
#pragma unroll
    for (int m = 0; m < 8; ++m)
#pragma unroll
      for (int n = 0; n < 4; ++n)
        acc[m][n] = __builtin_amdgcn_mfma_f32_16x16x32_bf16(av[m], bv[n], acc[m][n], 0, 0, 0);
    __builtin_amdgcn_s_setprio(0);
  };

  // Prologue: 3 tiles in flight.
  stage(0); stage(1); stage(2);

#pragma unroll 1
  for (int T = 0; T < 13; ++T) {
    WAITV8();          // tile T's 4 loads done; T+1,T+2 (8 loads) stay in flight
    BARRIER();
    stage(T + 3);      // refill: overwrites buf (T-1)&3, safe after barrier
    compute(T);
  }
  WAITV8(); BARRIER(); compute(13);
  WAITV4(); BARRIER(); compute(14);
  WAITV0(); BARRIER(); compute(15);

  // Epilogue: bias + store. C/D map: col = lane&15, row = (lane>>4)*4 + reg.
  const int h = regions[c];
  float bs[4];
#pragma unroll
  for (int n = 0; n < 4; ++n)
    bs[n] = bias_table[(size_t)h * D_DIM + d0 + wn * 64 + n * 16 + lr];

  float* ob = out + (size_t)c * B_DIM * D_DIM;
#pragma unroll
  for (int m = 0; m < 8; ++m) {
#pragma unroll
    for (int j = 0; j < 4; ++j) {
      const int bb = b0 + wm * 128 + m * 16 + lg * 4 + j;
      float* orow = ob + (size_t)bb * D_DIM + d0 + wn * 64 + lr;
#pragma unroll
      for (int n = 0; n < 4; ++n) orow[n * 16] = acc[m][n][j] + bs[n];
    }
  }
}

// ---------------------------------------------------------------------------
// Fallback: naive fp32 (only if ws is too small).
// ---------------------------------------------------------------------------
__global__ __launch_bounds__(256) void naive_ml(
    const float* __restrict__ in, const int* __restrict__ regions,
    const float* __restrict__ wt, const float* __restrict__ bias,
    float* __restrict__ out) {
  const int d = blockIdx.x * 256 + threadIdx.x;
  const int b = blockIdx.y;
  const int cz = blockIdx.z;
  const int h = regions[cz];
  const float* W = wt + (size_t)h * A_DIM * D_DIM + d;
  float acc = bias[(size_t)h * D_DIM + d];
  for (int a = 0; a < A_DIM; ++a) acc += in[(size_t)a * B_DIM + b] * W[(size_t)a * D_DIM];
  out[(size_t)cz * B_DIM * D_DIM + (size_t)b * D_DIM + d] = acc;
}

extern "C" void kernel_launch(void* const* d_in, const int* in_sizes, int n_in,
                              void* d_out, int out_size, void* d_ws, size_t ws_size,
                              hipStream_t stream) {
  const float* input = (const float*)d_in[0];
  const int* regions = (const int*)d_in[1];
  const float* wtab  = (const float*)d_in[2];
  const float* btab  = (const float*)d_in[3];
  float* out = (float*)d_out;
  const int C = in_sizes[1];  // n_regions = 128

  const size_t xt_bytes   = (size_t)B_DIM * A_DIM * 2;  // 1 MB
  const size_t per_region = (size_t)D_DIM * A_DIM * 2;  // 512 KB

  int cap = 0;
  if (ws_size > xt_bytes) {
    size_t r = (ws_size - xt_bytes) / per_region;
    cap = (r > (size_t)C) ? C : (int)r;
  }
  if (cap < 1) {
    naive_ml<<<dim3(D_DIM / 256, B_DIM, C), 256, 0, stream>>>(input, regions, wtab, btab, out);
    return;
  }

  unsigned short* Xt = (unsigned short*)d_ws;
  unsigned short* Wt = (unsigned short*)((char*)d_ws + xt_bytes);

  // Xt[b][a] <- input[a][b] (bf16)
  transpose_cvt<<<dim3(B_DIM / 64, A_DIM / 64, 1), 256, 0, stream>>>(
      input, Xt, nullptr, A_DIM, B_DIM);

  for (int c0 = 0; c0 < C; c0 += cap) {
    const int nc = (C - c0 < cap) ? (C - c0) : cap;
    transpose_cvt<<<dim3(D_DIM / 64, A_DIM / 64, nc), 256, 0, stream>>>(
        wtab, Wt, regions + c0, A_DIM, D_DIM);
    mlgemm<<<dim3(B_DIM / 256, D_DIM / 256, nc), 512, 0, stream>>>(
        Xt, Wt, btab, regions, c0, out);
  }
}

// Round 3
// 157.480 us; speedup vs baseline: 1.0867x; 1.0699x over previous
//
#include <hip/hip_runtime.h>
#include <stdint.h>

// out[c,b,d] = sum_a in[a,b] * W[reg[c],a,d] + bias[reg[c],d]
#define A_DIM 512   // in_features  (K)
#define B_DIM 1024  // batch        (M)
#define D_DIM 512   // out_features (N)

#define BM 256
#define BN 128
#define BK 32
#define NKT (A_DIM / BK)   // 16 K-tiles

typedef __bf16 bf16x8 __attribute__((ext_vector_type(8)));
typedef float f32x4 __attribute__((ext_vector_type(4)));

typedef __attribute__((address_space(1))) void gvoid_t;
typedef __attribute__((address_space(3))) void svoid_t;

#define WAITV6() asm volatile("s_waitcnt vmcnt(6)" ::: "memory")
#define WAITV0() asm volatile("s_waitcnt vmcnt(0)" ::: "memory")
#define BARRIER() do { asm volatile("" ::: "memory"); __builtin_amdgcn_s_barrier(); asm volatile("" ::: "memory"); } while (0)

__device__ __forceinline__ unsigned short f2bf(float f) {
  union { float f; unsigned u; } x; x.f = f;
  unsigned r = x.u + 0x7fffu + ((x.u >> 16) & 1u);
  return (unsigned short)(r >> 16);
}

__device__ __forceinline__ void gload16(const void* g, void* l) {
  __builtin_amdgcn_global_load_lds((gvoid_t*)g, (svoid_t*)l, 16, 0, 0);
}

// ---------------------------------------------------------------------------
// Pass 1: tiled transpose + fp32->bf16. 64x64 tiles, 256 threads.
// ---------------------------------------------------------------------------
__global__ __launch_bounds__(256) void transpose_cvt(
    const float* __restrict__ src, unsigned short* __restrict__ dst,
    const int* __restrict__ idx, int M, int N) {
  __shared__ float T[64][65];
  const int t = threadIdx.x;
  const size_t mat = idx ? (size_t)idx[blockIdx.z] : 0;
  const float* s = src + mat * (size_t)M * N;
  unsigned short* d = dst + (size_t)blockIdx.z * (size_t)M * N;
  const int m0 = blockIdx.y * 64, n0 = blockIdx.x * 64;

#pragma unroll
  for (int p = 0; p < 4; ++p) {
    const int mr = (t >> 4) + p * 16;
    const int n4 = (t & 15) * 4;
    const float4 v = *(const float4*)(s + (size_t)(m0 + mr) * N + n0 + n4);
    T[n4 + 0][mr] = v.x;
    T[n4 + 1][mr] = v.y;
    T[n4 + 2][mr] = v.z;
    T[n4 + 3][mr] = v.w;
  }
  __syncthreads();

#pragma unroll
  for (int p = 0; p < 2; ++p) {
    const int nr = (t >> 3) + p * 32;
    const int m8 = (t & 7) * 8;
    alignas(16) unsigned short tmp[8];
#pragma unroll
    for (int j = 0; j < 8; ++j) tmp[j] = f2bf(T[nr][m8 + j]);
    *(uint4*)(d + (size_t)(n0 + nr) * M + m0 + m8) = *(const uint4*)tmp;
  }
}

// ---------------------------------------------------------------------------
// Pass 2: 256x128-tile bf16 MFMA GEMM, BK=32, 4 waves (2Mx2N), 256 threads.
// Wave-tile 128x64 (375 B LDS-read per MFMA). 3-deep LDS ring (72 KiB) +
// ~190 VGPR -> 2 blocks/CU: store tails overlap the co-resident block.
// Counted vmcnt(6): 2 K-tiles always in flight; one barrier per tile.
// XOR involution swizzle (chunk ^= (row>>1)&3) applied to BOTH the
// global_load_lds source and the fragment-read chunk -> 2-way max (free).
// ---------------------------------------------------------------------------
__global__ __launch_bounds__(256, 2) void mlgemm(
    const unsigned short* __restrict__ Xt, const unsigned short* __restrict__ Wt,
    const float* __restrict__ bias_table, const int* __restrict__ regions,
    int c0, float* __restrict__ out) {
  __shared__ alignas(16) unsigned short As[3][BM][BK];  // 48 KiB
  __shared__ alignas(16) unsigned short Bs[3][BN][BK];  // 24 KiB

  const int t = threadIdx.x;
  const int w = t >> 6, l = t & 63;
  const int lr = l & 15, lg = l >> 4;
  const int wm = w >> 1, wn = w & 1;              // 2 (M) x 2 (N) waves
  const int b0 = blockIdx.x * BM, d0 = blockIdx.y * BN;
  const int cc = blockIdx.z, c = c0 + cc;

  f32x4 acc[8][4] = {};

  const size_t xbase = (size_t)b0 * A_DIM;
  const size_t wbase = ((size_t)cc * D_DIM + d0) * A_DIM;

  // lane's source chunk swizzle for staging: physical chunk (l&3) at LDS row
  // row0+(l>>2) holds global chunk (l&3) ^ ((l>>3)&3)  [row0 % 16 == 0]
  const int src_chunk = (l & 3) ^ ((l >> 3) & 3);
  const int lrow = l >> 2;

  auto stage = [&](int t_) {
    if (t_ >= NKT) return;
    const int buf = t_ % 3;
    const int koff = t_ * BK + src_chunk * 8;
    // A: 64 rows per wave (4 calls x 16 rows)
#pragma unroll
    for (int i = 0; i < 4; ++i) {
      const int row0 = w * 64 + i * 16;
      gload16(Xt + xbase + (size_t)(row0 + lrow) * A_DIM + koff, &As[buf][row0][0]);
    }
    // B: 32 rows per wave (2 calls x 16 rows)
#pragma unroll
    for (int i = 0; i < 2; ++i) {
      const int row0 = w * 32 + i * 16;
      gload16(Wt + wbase + (size_t)(row0 + lrow) * A_DIM + koff, &Bs[buf][row0][0]);
    }
  };

  const int rd_chunk = lg ^ ((lr >> 1) & 3);  // un-swizzle on read

  auto compute = [&](int t_) {
    const int buf = t_ % 3;
    bf16x8 av[8], bv[4];
#pragma unroll
    for (int m = 0; m < 8; ++m)
      av[m] = *(const bf16x8*)&As[buf][wm * 128 + m * 16 + lr][rd_chunk * 8];
#pragma unroll
    for (int n = 0; n < 4; ++n)
      bv[n] = *(const bf16x8*)&Bs[buf][wn * 64 + n * 16 + lr][rd_chunk * 8];
    __builtin_amdgcn_s_setprio(1);
#pragma unroll
    for (int m = 0; m < 8; ++m)
#pragma unroll
      for (int n = 0; n < 4; ++n)
        acc[m][n] = __builtin_amdgcn_mfma_f32_16x16x32_bf16(av[m], bv[n], acc[m][n], 0, 0, 0);
    __builtin_amdgcn_s_setprio(0);
  };

  // Prologue: 2 tiles in flight (12 loads/wave).
  stage(0); stage(1);

#pragma unroll 1
  for (int T = 0; T < NKT - 2; ++T) {
    WAITV6();        // own tile-T loads done; barrier makes it global
    BARRIER();
    stage(T + 2);    // refill buf (T+2)%3 == (T-1)%3, freed by this barrier
    compute(T);
  }
  WAITV6(); BARRIER(); compute(NKT - 2);
  WAITV0(); BARRIER(); compute(NKT - 1);

  // Epilogue: bias + store. C/D map: col = lane&15, row = (lane>>4)*4 + reg.
  const int h = regions[c];
  float bs[4];
#pragma unroll
  for (int n = 0; n < 4; ++n)
    bs[n] = bias_table[(size_t)h * D_DIM + d0 + wn * 64 + n * 16 + lr];

  float* ob = out + (size_t)c * B_DIM * D_DIM;
#pragma unroll
  for (int m = 0; m < 8; ++m) {
#pragma unroll
    for (int j = 0; j < 4; ++j) {
      const int bb = b0 + wm * 128 + m * 16 + lg * 4 + j;
      float* orow = ob + (size_t)bb * D_DIM + d0 + wn * 64 + lr;
#pragma unroll
      for (int n = 0; n < 4; ++n) orow[n * 16] = acc[m][n][j] + bs[n];
    }
  }
}

// ---------------------------------------------------------------------------
// Fallback: naive fp32 (only if ws is too small).
// ---------------------------------------------------------------------------
__global__ __launch_bounds__(256) void naive_ml(
    const float* __restrict__ in, const int* __restrict__ regions,
    const float* __restrict__ wt, const float* __restrict__ bias,
    float* __restrict__ out) {
  const int d = blockIdx.x * 256 + threadIdx.x;
  const int b = blockIdx.y;
  const int cz = blockIdx.z;
  const int h = regions[cz];
  const float* W = wt + (size_t)h * A_DIM * D_DIM + d;
  float acc = bias[(size_t)h * D_DIM + d];
  for (int a = 0; a < A_DIM; ++a) acc += in[(size_t)a * B_DIM + b] * W[(size_t)a * D_DIM];
  out[(size_t)cz * B_DIM * D_DIM + (size_t)b * D_DIM + d] = acc;
}

extern "C" void kernel_launch(void* const* d_in, const int* in_sizes, int n_in,
                              void* d_out, int out_size, void* d_ws, size_t ws_size,
                              hipStream_t stream) {
  const float* input = (const float*)d_in[0];
  const int* regions = (const int*)d_in[1];
  const float* wtab  = (const float*)d_in[2];
  const float* btab  = (const float*)d_in[3];
  float* out = (float*)d_out;
  const int C = in_sizes[1];  // n_regions = 128

  const size_t xt_bytes   = (size_t)B_DIM * A_DIM * 2;  // 1 MB
  const size_t per_region = (size_t)D_DIM * A_DIM * 2;  // 512 KB

  int cap = 0;
  if (ws_size > xt_bytes) {
    size_t r = (ws_size - xt_bytes) / per_region;
    cap = (r > (size_t)C) ? C : (int)r;
  }
  if (cap < 1) {
    naive_ml<<<dim3(D_DIM / 256, B_DIM, C), 256, 0, stream>>>(input, regions, wtab, btab, out);
    return;
  }

  unsigned short* Xt = (unsigned short*)d_ws;
  unsigned short* Wt = (unsigned short*)((char*)d_ws + xt_bytes);

  // Xt[b][a] <- input[a][b] (bf16)
  transpose_cvt<<<dim3(B_DIM / 64, A_DIM / 64, 1), 256, 0, stream>>>(
      input, Xt, nullptr, A_DIM, B_DIM);

  for (int c0 = 0; c0 < C; c0 += cap) {
    const int nc = (C - c0 < cap) ? (C - c0) : cap;
    transpose_cvt<<<dim3(D_DIM / 64, A_DIM / 64, nc), 256, 0, stream>>>(
        wtab, Wt, regions + c0, A_DIM, D_DIM);
    mlgemm<<<dim3(B_DIM / BM, D_DIM / BN, nc), 256, 0, stream>>>(
        Xt, Wt, btab, regions, c0, out);
  }
}

// Round 5
// 155.987 us; speedup vs baseline: 1.0971x; 1.0096x over previous
//
#include <hip/hip_runtime.h>
#include <stdint.h>

// out[c,b,d] = sum_a in[a,b] * W[reg[c],a,d] + bias[reg[c],d]
#define A_DIM 512   // in_features  (K)
#define B_DIM 1024  // batch        (M)
#define D_DIM 512   // out_features (N)
#define NKT   16    // K-tiles of 32

typedef __bf16 bf16x8 __attribute__((ext_vector_type(8)));
typedef float f32x4 __attribute__((ext_vector_type(4)));
typedef unsigned u32x2 __attribute__((ext_vector_type(2)));

typedef __attribute__((address_space(1))) void gvoid_t;
typedef __attribute__((address_space(3))) void svoid_t;

#define WAITV8() asm volatile("s_waitcnt vmcnt(8)" ::: "memory")
#define WAITV0() asm volatile("s_waitcnt vmcnt(0)" ::: "memory")
#define LGKM0()  asm volatile("s_waitcnt lgkmcnt(0)" ::: "memory")
#define FENCE()  asm volatile("" ::: "memory")
#define BARRIER() do { FENCE(); __builtin_amdgcn_s_barrier(); FENCE(); } while (0)

// fp32 -> bf16 RNE (proven R1/R3)
__device__ __forceinline__ unsigned short f2bf(float f) {
  union { float f; unsigned u; } x; x.f = f;
  unsigned r = x.u + 0x7fffu + ((x.u >> 16) & 1u);
  return (unsigned short)(r >> 16);
}

__device__ __forceinline__ void gload16(const void* g, void* l) {
  __builtin_amdgcn_global_load_lds((gvoid_t*)g, (svoid_t*)l, 16, 0, 0);
}

// ---------------------------------------------------------------------------
// Prepass (X only): Xt[b][a] <- bf16(input[a][b]). R1-proven verbatim.
// ---------------------------------------------------------------------------
__global__ __launch_bounds__(256) void transpose_cvt(
    const float* __restrict__ src, unsigned short* __restrict__ dst,
    int M, int N) {
  __shared__ float T[64][65];
  const int t = threadIdx.x;
  const int m0 = blockIdx.y * 64, n0 = blockIdx.x * 64;

#pragma unroll
  for (int p = 0; p < 4; ++p) {
    const int mr = (t >> 4) + p * 16;
    const int n4 = (t & 15) * 4;
    const float4 v = *(const float4*)(src + (size_t)(m0 + mr) * N + n0 + n4);
    T[n4 + 0][mr] = v.x;
    T[n4 + 1][mr] = v.y;
    T[n4 + 2][mr] = v.z;
    T[n4 + 3][mr] = v.w;
  }
  __syncthreads();

#pragma unroll
  for (int p = 0; p < 2; ++p) {
    const int nr = (t >> 3) + p * 32;
    const int m8 = (t & 7) * 8;
    alignas(16) unsigned short tmp[8];
#pragma unroll
    for (int j = 0; j < 8; ++j) tmp[j] = f2bf(T[nr][m8 + j]);
    *(uint4*)(dst + (size_t)(n0 + nr) * M + m0 + m8) = *(const uint4*)tmp;
  }
}

// ---------------------------------------------------------------------------
// Fused GEMM: 256x128 tile, BK=32, 4 waves (2Mx2N), 256 threads.
// A: Xt bf16 via global_load_lds 3-ring, XOR chunk swizzle (R3-proven).
// B: W fp32 -> regs -> f2bf pairs (k,k+1 packed per u32) -> LDS Bsu[16][130]
//    (+2 pad => read bank (2kp+d)%32, 2-way = free) -> 4x ds_read_b32/frag.
// Both fragments hold k in natural ascending order -> no permutation.
// 2 tiles in flight, vmcnt(8) counted waits, 1 barrier/tile, setprio MFMA.
// ---------------------------------------------------------------------------
__global__ __launch_bounds__(256, 2) void mlgemm_fused(
    const unsigned short* __restrict__ Xt, const float* __restrict__ wtab,
    const float* __restrict__ bias_table, const int* __restrict__ regions,
    float* __restrict__ out) {
  __shared__ alignas(16) unsigned short As[3][256][32];  // 48 KiB
  __shared__ alignas(16) unsigned Bsu[2][16][130];       // 16.25 KiB

  const int t = threadIdx.x;
  const int w = t >> 6, l = t & 63;
  const int lr = l & 15, lg = l >> 4;
  const int wm = w >> 1, wn = w & 1;          // 2 (M) x 2 (N) waves
  const int b0 = blockIdx.x * 256, d0blk = blockIdx.y * 128;
  const int c = blockIdx.z;
  const int h = regions[c];

  const unsigned short* Xbase = Xt + (size_t)b0 * A_DIM;
  const float* Wbase = wtab + (size_t)h * A_DIM * D_DIM + d0blk;

  f32x4 acc[8][4] = {};

  // A staging (R3-proven): linear LDS dest, XOR-swizzled source chunk.
  const int a_src_chunk = (l & 3) ^ ((l >> 3) & 3);
  const int a_lrow = l >> 2;
  // B staging lane constants: k-pair index and d-run.
  const int kp_base = (w & 1) * 4 + ((l >> 3) & 3);          // + r*8
  const int bd0 = 4 * (l & 7) + 32 * (l >> 5) + 64 * (w >> 1);

  f32x4 bregE[4], bregO[4];   // [r*2 + khalf], r = 0,1

  auto issueA = [&](int T) {
    const int buf = T % 3;
    const int koff = T * 32 + a_src_chunk * 8;
#pragma unroll
    for (int i = 0; i < 4; ++i) {
      const int row0 = w * 64 + i * 16;
      gload16(Xbase + (size_t)(row0 + a_lrow) * A_DIM + koff, &As[buf][row0][0]);
    }
  };
  auto ldB = [&](int T, f32x4 (&breg)[4]) {
#pragma unroll
    for (int r = 0; r < 2; ++r) {
      const int kp = r * 8 + kp_base;
      const float* p = Wbase + (size_t)(T * 32 + kp * 2) * D_DIM + bd0;
      breg[r * 2 + 0] = *(const f32x4*)p;           // k = 2kp
      breg[r * 2 + 1] = *(const f32x4*)(p + D_DIM); // k = 2kp+1
    }
  };
  auto writeB = [&](int T, f32x4 (&breg)[4]) {
#pragma unroll
    for (int r = 0; r < 2; ++r) {
      const int kp = r * 8 + kp_base;
      unsigned pk[4];
#pragma unroll
      for (int i = 0; i < 4; ++i)
        pk[i] = (unsigned)f2bf(breg[r * 2][i]) |
                ((unsigned)f2bf(breg[r * 2 + 1][i]) << 16);
      unsigned* dst = &Bsu[T & 1][kp][bd0];
      *(u32x2*)(dst + 0) = u32x2{pk[0], pk[1]};
      *(u32x2*)(dst + 2) = u32x2{pk[2], pk[3]};
    }
  };

  auto mfmaStep = [&](int T) {
    const int abuf = T % 3, bbuf = T & 1;
    bf16x8 av[8], bv[4];
#pragma unroll
    for (int m = 0; m < 8; ++m) {
      const int row = wm * 128 + m * 16 + lr;
      av[m] = *(const bf16x8*)&As[abuf][row][(lg ^ ((lr >> 1) & 3)) * 8];
    }
#pragma unroll
    for (int n = 0; n < 4; ++n) {
      const int d = wn * 64 + n * 16 + lr;
      union { unsigned u[4]; bf16x8 v; } ub;
#pragma unroll
      for (int i = 0; i < 4; ++i) ub.u[i] = Bsu[bbuf][4 * lg + i][d];
      bv[n] = ub.v;
    }
    __builtin_amdgcn_s_setprio(1);
#pragma unroll
    for (int m = 0; m < 8; ++m)
#pragma unroll
      for (int n = 0; n < 4; ++n)
        acc[m][n] = __builtin_amdgcn_mfma_f32_16x16x32_bf16(av[m], bv[n], acc[m][n], 0, 0, 0);
    __builtin_amdgcn_s_setprio(0);
  };

  // Prologue: 2 tiles in flight (8 VMEM/wave/tile: 4 gload_lds + 4 float4).
  issueA(0); ldB(0, bregE);
  issueA(1); ldB(1, bregO);

#pragma unroll 1
  for (int T = 0; T < NKT - 2; T += 2) {
    WAITV8();                       // tile T's 8 done; T+1 stays in flight
    writeB(T, bregE);
    LGKM0(); BARRIER();
    issueA(T + 2); ldB(T + 2, bregE); FENCE();
    mfmaStep(T);

    WAITV8();
    writeB(T + 1, bregO);
    LGKM0(); BARRIER();
    issueA(T + 3); ldB(T + 3, bregO); FENCE();
    mfmaStep(T + 1);
  }
  WAITV8();
  writeB(NKT - 2, bregE);
  LGKM0(); BARRIER();
  mfmaStep(NKT - 2);
  WAITV0();
  writeB(NKT - 1, bregO);
  LGKM0(); BARRIER();
  mfmaStep(NKT - 1);

  // Epilogue (proven): C/D map col = lane&15, row = (lane>>4)*4 + reg.
  float bs[4];
#pragma unroll
  for (int n = 0; n < 4; ++n)
    bs[n] = bias_table[(size_t)h * D_DIM + d0blk + wn * 64 + n * 16 + lr];

  float* ob = out + (size_t)c * B_DIM * D_DIM;
#pragma unroll
  for (int m = 0; m < 8; ++m) {
#pragma unroll
    for (int j = 0; j < 4; ++j) {
      const int bb = b0 + wm * 128 + m * 16 + lg * 4 + j;
      float* orow = ob + (size_t)bb * D_DIM + d0blk + wn * 64 + lr;
#pragma unroll
      for (int n = 0; n < 4; ++n) orow[n * 16] = acc[m][n][j] + bs[n];
    }
  }
}

// ---------------------------------------------------------------------------
// Fallback: naive fp32 (only if ws can't hold Xt).
// ---------------------------------------------------------------------------
__global__ __launch_bounds__(256) void naive_ml(
    const float* __restrict__ in, const int* __restrict__ regions,
    const float* __restrict__ wt, const float* __restrict__ bias,
    float* __restrict__ out) {
  const int d = blockIdx.x * 256 + threadIdx.x;
  const int b = blockIdx.y;
  const int cz = blockIdx.z;
  const int hh = regions[cz];
  const float* W = wt + (size_t)hh * A_DIM * D_DIM + d;
  float acc = bias[(size_t)hh * D_DIM + d];
  for (int a = 0; a < A_DIM; ++a) acc += in[(size_t)a * B_DIM + b] * W[(size_t)a * D_DIM];
  out[(size_t)cz * B_DIM * D_DIM + (size_t)b * D_DIM + d] = acc;
}

extern "C" void kernel_launch(void* const* d_in, const int* in_sizes, int n_in,
                              void* d_out, int out_size, void* d_ws, size_t ws_size,
                              hipStream_t stream) {
  const float* input = (const float*)d_in[0];
  const int* regions = (const int*)d_in[1];
  const float* wtab  = (const float*)d_in[2];
  const float* btab  = (const float*)d_in[3];
  float* out = (float*)d_out;
  const int C = in_sizes[1];  // n_regions = 128

  const size_t xt_bytes = (size_t)B_DIM * A_DIM * 2;  // 1 MB

  if (ws_size < xt_bytes) {
    naive_ml<<<dim3(D_DIM / 256, B_DIM, C), 256, 0, stream>>>(input, regions, wtab, btab, out);
    return;
  }

  unsigned short* Xt = (unsigned short*)d_ws;

  transpose_cvt<<<dim3(B_DIM / 64, A_DIM / 64), 256, 0, stream>>>(
      input, Xt, A_DIM, B_DIM);
  mlgemm_fused<<<dim3(B_DIM / 256, D_DIM / 128, C), 256, 0, stream>>>(
      Xt, wtab, btab, regions, out);
}